// Round 12
// baseline (835.824 us; speedup 1.0000x reference)
//
#include <hip/hip_runtime.h>
#include <hip/hip_fp16.h>
#include <math.h>

#define NREP 16
#define RDIM 16
#define NS   16
#define NC   6
#define H1   144
#define DBINS 64

static __device__ __forceinline__ float leaky(float v) { return v > 0.0f ? v : 0.01f * v; }

// ---------- per-graph mean (LDS-binned: batch is sorted) ----------
__global__ void k_graph_sum(const float* __restrict__ pos, const int* __restrict__ batch,
                            int N, float* __restrict__ gsum, float* __restrict__ gcnt) {
  __shared__ float bx[320], by[320], bc[320];
  int t = threadIdx.x;
  int start = blockIdx.x * 256;
  int n = start + t;
  int b0 = batch[min(start, N - 1)];
  int span = batch[min(start + 255, N - 1)] - b0;   // batch sorted -> >=0
  bool useLds = (span < 320);
  if (useLds) {
    for (int i = t; i <= span; i += 256) { bx[i] = 0.f; by[i] = 0.f; bc[i] = 0.f; }
    __syncthreads();
    if (n < N) {
      int rb = batch[n] - b0;
      atomicAdd(&bx[rb], pos[2 * n + 0]);
      atomicAdd(&by[rb], pos[2 * n + 1]);
      atomicAdd(&bc[rb], 1.0f);
    }
    __syncthreads();
    for (int i = t; i <= span; i += 256) {
      if (bc[i] != 0.0f) {
        atomicAdd(&gsum[2 * (b0 + i) + 0], bx[i]);
        atomicAdd(&gsum[2 * (b0 + i) + 1], by[i]);
        atomicAdd(&gcnt[b0 + i], bc[i]);
      }
    }
  } else if (n < N) {
    int b = batch[n];
    atomicAdd(&gsum[2 * b + 0], pos[2 * n + 0]);
    atomicAdd(&gsum[2 * b + 1], pos[2 * n + 1]);
    atomicAdd(&gcnt[b], 1.0f);
  }
}

__global__ void k_center(const float* __restrict__ pos, const int* __restrict__ batch, int N,
                         const float* __restrict__ gsum, const float* __restrict__ gcnt,
                         float* __restrict__ posc, float* __restrict__ cthn, float* __restrict__ sthn) {
  int n = blockIdx.x * blockDim.x + threadIdx.x;
  if (n >= N) return;
  int b = batch[n];
  float invc = 1.0f / fmaxf(gcnt[b], 1.0f);
  float px = pos[2 * n + 0] - gsum[2 * b + 0] * invc;
  float py = pos[2 * n + 1] - gsum[2 * b + 1] * invc;
  posc[2 * n + 0] = px;
  posc[2 * n + 1] = py;
  float r = sqrtf(px * px + py * py);
  if (r > 0.0f) { cthn[n] = px / r; sthn[n] = py / r; }
  else          { cthn[n] = 1.0f;   sthn[n] = 0.0f; }
}

// ---------- CSR build ----------
__global__ void k_count(const int* __restrict__ ei, int E, int* __restrict__ cnt) {
  int e = blockIdx.x * blockDim.x + threadIdx.x;
  if (e >= E) return;
  atomicAdd(&cnt[ei[e]], 1);
}

// ---------- degree-sort permutation (64-bin counting sort, LDS-privatized) ----------
__global__ void k_dhist(const int* __restrict__ cnt, int N, int* __restrict__ dhist) {
  __shared__ int lh[DBINS];
  int t = threadIdx.x;
  int n = blockIdx.x * 256 + t;
  if (t < DBINS) lh[t] = 0;
  __syncthreads();
  if (n < N) atomicAdd(&lh[min(cnt[n], DBINS - 1)], 1);
  __syncthreads();
  if (t < DBINS && lh[t] > 0) atomicAdd(&dhist[t], lh[t]);
}

__global__ void k_dscan(const int* __restrict__ dhist, int* __restrict__ dcur) {
  __shared__ int sd[DBINS];
  int t = threadIdx.x;
  int v = dhist[t];
  sd[t] = v;
  __syncthreads();
  for (int o = 1; o < DBINS; o <<= 1) {
    int u = (t >= o) ? sd[t - o] : 0;
    __syncthreads();
    sd[t] += u;
    __syncthreads();
  }
  dcur[t] = sd[t] - v;   // exclusive base, doubles as cursor
}

// per-block chunk reservation: 256 LDS atomics + <=64 global atomics per block
__global__ void k_dfill(const int* __restrict__ cnt, int N, int* __restrict__ dcur,
                        int* __restrict__ perm) {
  __shared__ int lh[DBINS];
  __shared__ int base[DBINS];
  int t = threadIdx.x;
  int n = blockIdx.x * 256 + t;
  if (t < DBINS) lh[t] = 0;
  __syncthreads();
  int b = 0, lr = 0;
  if (n < N) {
    b = min(cnt[n], DBINS - 1);
    lr = atomicAdd(&lh[b], 1);           // local rank within (block, bin)
  }
  __syncthreads();
  if (t < DBINS && lh[t] > 0) base[t] = atomicAdd(&dcur[t], lh[t]);
  __syncthreads();
  if (n < N) perm[base[b] + lr] = n;
}

// ---------- parallel 3-phase exclusive scan of cnt[0..N) into off ----------
__global__ void k_scan1(const int* __restrict__ cnt, int N,
                        int* __restrict__ off, int* __restrict__ bsum) {
  __shared__ int sd[1024];
  int t = threadIdx.x;
  int i = blockIdx.x * 1024 + t;
  int v = (i < N) ? cnt[i] : 0;
  sd[t] = v;
  __syncthreads();
  for (int o = 1; o < 1024; o <<= 1) {
    int u = (t >= o) ? sd[t - o] : 0;
    __syncthreads();
    sd[t] += u;
    __syncthreads();
  }
  if (i < N) off[i] = sd[t] - v;          // block-local exclusive
  if (t == 1023) bsum[blockIdx.x] = sd[1023];
}

__global__ void k_scan2(int* __restrict__ bsum, int nb) {
  __shared__ int sd[1024];
  int t = threadIdx.x;
  int v = (t < nb) ? bsum[t] : 0;
  sd[t] = v;
  __syncthreads();
  for (int o = 1; o < 1024; o <<= 1) {
    int u = (t >= o) ? sd[t - o] : 0;
    __syncthreads();
    sd[t] += u;
    __syncthreads();
  }
  if (t < nb) bsum[t] = sd[t] - v;        // exclusive block bases
}

__global__ void k_scan3(int* __restrict__ off, const int* __restrict__ bsum, int N, int E) {
  int i = blockIdx.x * 1024 + threadIdx.x;
  if (i < N) off[i] += bsum[blockIdx.x];
  if (i == N) off[N] = E;                 // total is exactly E
}

// csr[k] = (sp' = sqrt2*sin(pi d)/(d+eps), c2 = 2*cos(pi d), col-bits, d)
// Also folds the node-init reductions (sum cos, sum sin, sum d) into nacc*
// via fire-and-forget atomics — dx/d, dy/d are free here.
__global__ void k_build(const float* __restrict__ posc, const int* __restrict__ ei, int E,
                        const int* __restrict__ off, int* __restrict__ cursor,
                        float4* __restrict__ csr,
                        float* __restrict__ naccC, float* __restrict__ naccS,
                        float* __restrict__ naccD) {
  int e = blockIdx.x * blockDim.x + threadIdx.x;
  if (e >= E) return;
  int r = ei[e], cl = ei[E + e];
  float dx = posc[2 * r + 0] - posc[2 * cl + 0];
  float dy = posc[2 * r + 1] - posc[2 * cl + 1];
  float d = sqrtf(dx * dx + dy * dy);
  float cth, sth;
  if (d > 0.0f) { float inv = 1.0f / d; cth = dx * inv; sth = dy * inv; }
  else          { cth = 1.0f; sth = 0.0f; }
  atomicAdd(&naccC[r], cth);
  atomicAdd(&naccS[r], sth);
  atomicAdd(&naccD[r], d);
  float sp, cp;
  sincospif(d, &sp, &cp);
  float spp = 1.41421356237309515f * sp / (d + 1e-8f);
  int p = atomicAdd(&cursor[r], 1);
  csr[off[r] + p] = make_float4(spp, 2.0f * cp, __int_as_float(cl), d);
}

// ---------- node init: pure streaming (reductions already done in k_build) ----------
__global__ void k_node_init(int N, const int* __restrict__ cnt,
                            const float* __restrict__ naccC, const float* __restrict__ naccS,
                            const float* __restrict__ naccD,
                            const float* __restrict__ Wer, const float* __restrict__ wse,
                            const float* __restrict__ bse,
                            float* __restrict__ xr, float* __restrict__ xs) {
  int n = blockIdx.x * blockDim.x + threadIdx.x;
  if (n >= N) return;
  float id = 1.0f / fmaxf((float)cnt[n], 1.0f);
  float C = naccC[n] * id;
  float S = naccS[n] * id;
  float dm = naccD[n] * id;
  size_t nb = (size_t)n * (2 * NREP);
#pragma unroll
  for (int j = 0; j < NREP; j++) {
    float w0 = Wer[2 * j], w1 = Wer[2 * j + 1];
    xr[nb + 2 * j + 0] = C * w0 - S * w1;
    xr[nb + 2 * j + 1] = S * w0 + C * w1;
  }
  size_t ns = (size_t)n * NS;
#pragma unroll
  for (int t = 0; t < NS; t++) xs[ns + t] = leaky(dm * wse[t] + bse[t]);
}

// ---------- per-node precompute, fp16-packed: yzg = {h2(y0,y1), h2(z,gate)} ----------
__global__ void __launch_bounds__(256) k_pre(
    int N, const float* __restrict__ xr, const float* __restrict__ xs,
    const float* __restrict__ Wmix, const float* __restrict__ Ws1, const float* __restrict__ bs1,
    const float* __restrict__ Wgate, const float* __restrict__ bgate,
    uint2* __restrict__ yzg) {
  int idx = blockIdx.x * 256 + threadIdx.x;
  int n = idx >> 4, r = idx & 15;
  if (n >= N) return;
  float wmx[16], wsa[16], wgt[16];
  const float4* wm4 = (const float4*)(Wmix + r * 16);   // row r of Wmix (contiguous)
#pragma unroll
  for (int j = 0; j < 4; j++) {
    float4 w = wm4[j];
    wmx[4 * j + 0] = w.x; wmx[4 * j + 1] = w.y; wmx[4 * j + 2] = w.z; wmx[4 * j + 3] = w.w;
  }
#pragma unroll
  for (int q = 0; q < 16; q++) wsa[q] = Ws1[q * 16 + r];     // xs-part column r
#pragma unroll
  for (int q = 0; q < 16; q++) wgt[q] = Wgate[q * 16 + r];   // gate column r

  float x0[16], x1[16], xv[16];
  const float4* xr4 = (const float4*)(xr + (size_t)n * 32);
#pragma unroll
  for (int j = 0; j < 8; j++) {
    float4 u = xr4[j];
    x0[2 * j + 0] = u.x; x1[2 * j + 0] = u.y;
    x0[2 * j + 1] = u.z; x1[2 * j + 1] = u.w;
  }
  const float4* xs4 = (const float4*)(xs + (size_t)n * 16);
#pragma unroll
  for (int j = 0; j < 4; j++) {
    float4 u = xs4[j];
    xv[4 * j + 0] = u.x; xv[4 * j + 1] = u.y; xv[4 * j + 2] = u.z; xv[4 * j + 3] = u.w;
  }
  float y0 = 0.f, y1 = 0.f;
#pragma unroll
  for (int j = 0; j < 16; j++) { y0 += wmx[j] * x0[j]; y1 += wmx[j] * x1[j]; }
  float z = bs1[r], gt = bgate[r];
#pragma unroll
  for (int q = 0; q < 16; q++) { z += wsa[q] * xv[q]; gt += wgt[q] * xv[q]; }
  gt = 1.0f / (1.0f + __expf(-gt));
  __half2 hA = __floats2half2_rn(y0, y1);
  __half2 hB = __floats2half2_rn(z, gt);
  uint2 w2;
  w2.x = *(unsigned int*)&hA;
  w2.y = *(unsigned int*)&hB;
  yzg[(size_t)n * 16 + r] = w2;
}

// ---------- EqBlock layer: 16 lanes/node, degree-sorted, distance-2/3 prefetch ----------
__global__ void __launch_bounds__(256) k_layer(
    int N, const int* __restrict__ off, const float4* __restrict__ csr,
    const uint2* __restrict__ yzg, const int* __restrict__ perm,
    const float* __restrict__ Wg, const float* __restrict__ bg,
    const float* __restrict__ Ws1,   // layer base; demb rows are 16..31
    float* xr, float* xs) {
  int idx = blockIdx.x * 256 + threadIdx.x;
  int g = idx >> 4, r = idx & 15;
  if (g >= N) return;
  int n = perm[g];                      // degree-sorted: waves get equal-degree nodes
  float wg[16], ws[16];
#pragma unroll
  for (int q = 0; q < 16; q++) wg[q] = Wg[q * 16 + r];
#pragma unroll
  for (int q = 0; q < 16; q++) ws[q] = Ws1[(16 + q) * 16 + r];
  float bgr = bg[r];

  int a = off[n], bnd = off[n + 1];
  float acc0 = 0.f, acc1 = 0.f, accs = 0.f;
  if (a < bnd) {
    int last = bnd - 1;
    // deep pipeline: csr prefetched 3 ahead, yzg 2 ahead — both loads issue with
    // register-ready operands, Y consumed ~2 iterations (200+ cyc) after issue.
    float4 v0 = csr[a];
    float4 v1 = csr[min(a + 1, last)];
    float4 v2 = csr[min(a + 2, last)];
    uint2 Y0 = yzg[(size_t)__float_as_int(v0.z) * 16 + r];
    uint2 Y1 = yzg[(size_t)__float_as_int(v1.z) * 16 + r];
    for (int k = a; k < bnd; k++) {
      float4 v3 = csr[min(k + 3, last)];                       // prefetch csr
      uint2 Y2 = yzg[(size_t)__float_as_int(v2.z) * 16 + r];   // prefetch Y (v2 ready)
      // compute on v0 (radial chain independent of the gather)
      float skm1 = 0.f, sk = v0.x, c2 = v0.y;
      float g1 = bgr, dot = 0.f;
#pragma unroll
      for (int q = 0; q < RDIM; q++) {
        g1  = __builtin_fmaf(sk, wg[q], g1);
        dot = __builtin_fmaf(sk, ws[q], dot);
        float sn = __builtin_fmaf(c2, sk, -skm1);
        skm1 = sk; sk = sn;
      }
      // consume gathered Y0 only at the end of the iteration
      float2 f01 = __half22float2(*(__half2*)&Y0.x);
      float2 fzg = __half22float2(*(__half2*)&Y0.y);
      acc0 = __builtin_fmaf(g1, f01.x, acc0);
      acc1 = __builtin_fmaf(g1, f01.y, acc1);
      accs += leaky(dot + fzg.x);
      v0 = v1; v1 = v2; v2 = v3; Y0 = Y1; Y1 = Y2;
    }
  }
  float id = 1.0f / fmaxf((float)(bnd - a), 1.0f);
  uint2 Yg = yzg[(size_t)n * 16 + r];
  float gt = __half22float2(*(__half2*)&Yg.y).y;
  float2* xr2 = (float2*)xr;
  float2 x = xr2[(size_t)n * 16 + r];
  x.x += acc0 * id * gt;
  x.y += acc1 * id * gt;
  xr2[(size_t)n * 16 + r] = x;            // in-place safe: (n,r) written only by this thread
  xs[(size_t)n * 16 + r] += accs * id;
}

// ---------- final rotate-out + MLP (W1^T in LDS, 2-h ILP) + binned graph sum ----------
__global__ void __launch_bounds__(128) k_final(
    int N, const float* __restrict__ xr, const float* __restrict__ xs,
    const float* __restrict__ cthn, const float* __restrict__ sthn,
    const int* __restrict__ batch,
    const float* __restrict__ W1, const float* __restrict__ b1,
    const float* __restrict__ W2, const float* __restrict__ b2,
    float* __restrict__ out) {
  __shared__ float W1t[48 * H1];
  __shared__ float W2s[H1 * 6];
  __shared__ float b1s[H1];
  __shared__ float obin[320 * 6];
  int t = threadIdx.x;
  for (int i = t; i < 48 * H1; i += 128) { int q = i / H1, h = i - q * H1; W1t[h * 48 + q] = W1[i]; }
  for (int i = t; i < H1 * 6; i += 128) W2s[i] = W2[i];
  for (int i = t; i < H1; i += 128) b1s[i] = b1[i];

  int start = blockIdx.x * 128;
  int n = start + t;
  int b0 = batch[min(start, N - 1)];
  int span = batch[min(start + 127, N - 1)] - b0;
  bool useLds = (span < 320);
  if (useLds) for (int i = t; i < (span + 1) * 6; i += 128) obin[i] = 0.f;
  __syncthreads();

  float u[NC];
  bool act = (n < N);
  if (act) {
    float4 xcv[12];
    const float4* xs4 = (const float4*)(xs + (size_t)n * NS);
#pragma unroll
    for (int j = 0; j < 4; j++) xcv[j] = xs4[j];
    float c = cthn[n], s = sthn[n];
    const float4* xr4 = (const float4*)(xr + (size_t)n * 32);
#pragma unroll
    for (int j = 0; j < 8; j++) {
      float4 v = xr4[j];
      xcv[4 + j] = make_float4(c * v.x - s * v.y, s * v.x + c * v.y,
                               c * v.z - s * v.w, s * v.z + c * v.w);
    }
#pragma unroll
    for (int q = 0; q < NC; q++) u[q] = b2[q];
    for (int h = 0; h < H1; h += 2) {
      const float4* w0 = (const float4*)&W1t[h * 48];
      const float4* w1 = (const float4*)&W1t[(h + 1) * 48];
      float4 a0 = make_float4(0.f, 0.f, 0.f, 0.f);
      float4 a1 = make_float4(0.f, 0.f, 0.f, 0.f);
#pragma unroll
      for (int j = 0; j < 12; j++) {
        float4 x = xcv[j];
        float4 w = w0[j];
        a0.x += x.x * w.x; a0.y += x.y * w.y; a0.z += x.z * w.z; a0.w += x.w * w.w;
        float4 v = w1[j];
        a1.x += x.x * v.x; a1.y += x.y * v.y; a1.z += x.z * v.z; a1.w += x.w * v.w;
      }
      float aa0 = leaky((a0.x + a0.y) + (a0.z + a0.w) + b1s[h]);
      float aa1 = leaky((a1.x + a1.y) + (a1.z + a1.w) + b1s[h + 1]);
#pragma unroll
      for (int q = 0; q < NC; q++)
        u[q] += aa0 * W2s[h * 6 + q] + aa1 * W2s[(h + 1) * 6 + q];
    }
  }
  if (useLds) {
    if (act) {
      int rb = batch[n] - b0;
#pragma unroll
      for (int q = 0; q < NC; q++) atomicAdd(&obin[rb * 6 + q], u[q]);
    }
    __syncthreads();
    for (int i = t; i < (span + 1) * 6; i += 128) atomicAdd(&out[b0 * 6 + i], obin[i]);
  } else if (act) {
    int b = batch[n];
#pragma unroll
    for (int q = 0; q < NC; q++) atomicAdd(&out[b * 6 + q], u[q]);
  }
}

extern "C" void kernel_launch(void* const* d_in, const int* in_sizes, int n_in,
                              void* d_out, int out_size, void* d_ws, size_t ws_size,
                              hipStream_t stream) {
  const float* pos   = (const float*)d_in[0];
  const float* Wer   = (const float*)d_in[1];
  const float* wse   = (const float*)d_in[2];
  const float* bse   = (const float*)d_in[3];
  const float* Wg    = (const float*)d_in[4];
  const float* bg    = (const float*)d_in[5];
  const float* Wmix  = (const float*)d_in[6];
  const float* Wgate = (const float*)d_in[7];
  const float* bgate = (const float*)d_in[8];
  const float* Ws1   = (const float*)d_in[9];
  const float* bs1   = (const float*)d_in[10];
  const float* W1    = (const float*)d_in[11];
  const float* b1    = (const float*)d_in[12];
  const float* W2    = (const float*)d_in[13];
  const float* b2    = (const float*)d_in[14];
  const int*   ei    = (const int*)d_in[15];
  const int*   batch = (const int*)d_in[16];
  float* out = (float*)d_out;

  int N = in_sizes[0] / 2;
  int E = in_sizes[15] / 2;
  int G = out_size / NC;

  // ---- workspace layout (~63 MB for N=100k, E=1.6M) ----
  float* W = (float*)d_ws;
  size_t o = 0;
  float* gsum   = W + o; o += (size_t)2 * G;
  float* gcnt   = W + o; o += (size_t)G;
  int*   cnt    = (int*)(W + o); o += (size_t)N;
  int*   cursor = (int*)(W + o); o += (size_t)N;
  int*   dhist  = (int*)(W + o); o += (size_t)DBINS;
  float* naccC  = W + o; o += (size_t)N;
  float* naccS  = W + o; o += (size_t)N;
  float* naccD  = W + o; o += (size_t)N;
  size_t zero_bytes = o * 4;
  o = (o + 3) & ~(size_t)3;
  float* posc   = W + o; o += (size_t)2 * N;
  float* cthn   = W + o; o += (size_t)N;
  float* sthn   = W + o; o += (size_t)N;
  int*   off    = (int*)(W + o); o += (size_t)N + 1; o = (o + 3) & ~(size_t)3;
  int*   bsum   = (int*)(W + o); o += (size_t)1024;
  int*   dcur   = (int*)(W + o); o += (size_t)DBINS;
  int*   perm   = (int*)(W + o); o += (size_t)N; o = (o + 3) & ~(size_t)3;
  float4* csr   = (float4*)(W + o); o += (size_t)4 * E;
  uint2* yzg    = (uint2*)(W + o); o += (size_t)32 * N;
  float* xr     = W + o; o += (size_t)N * 32;
  float* xs     = W + o; o += (size_t)N * 16;
  (void)ws_size;

  hipMemsetAsync(d_ws, 0, zero_bytes, stream);
  hipMemsetAsync(d_out, 0, (size_t)out_size * 4, stream);

  int nbN  = (N + 255) / 256;
  int nbE  = (E + 255) / 256;
  int nbN16 = ((size_t)N * 16 + 255) / 256;
  int nbS  = (N + 1023) / 1024;           // scan blocks (98 for N=100k, <=1024 required)
  int nbS3 = (N + 1 + 1023) / 1024;
  int nbF  = (N + 127) / 128;             // k_final blocks

  k_graph_sum<<<nbN, 256, 0, stream>>>(pos, batch, N, gsum, gcnt);
  k_center<<<nbN, 256, 0, stream>>>(pos, batch, N, gsum, gcnt, posc, cthn, sthn);
  k_count<<<nbE, 256, 0, stream>>>(ei, E, cnt);
  k_dhist<<<nbN, 256, 0, stream>>>(cnt, N, dhist);
  k_dscan<<<1, DBINS, 0, stream>>>(dhist, dcur);
  k_dfill<<<nbN, 256, 0, stream>>>(cnt, N, dcur, perm);
  k_scan1<<<nbS, 1024, 0, stream>>>(cnt, N, off, bsum);
  k_scan2<<<1, 1024, 0, stream>>>(bsum, nbS);
  k_scan3<<<nbS3, 1024, 0, stream>>>(off, bsum, N, E);
  k_build<<<nbE, 256, 0, stream>>>(posc, ei, E, off, cursor, csr, naccC, naccS, naccD);
  k_node_init<<<nbN, 256, 0, stream>>>(N, cnt, naccC, naccS, naccD, Wer, wse, bse, xr, xs);

  for (int i = 0; i < 3; i++) {
    k_pre<<<nbN16, 256, 0, stream>>>(N, xr, xs,
                                     Wmix + i * 256, Ws1 + i * 512, bs1 + i * 16,
                                     Wgate + i * 256, bgate + i * 16, yzg);
    k_layer<<<nbN16, 256, 0, stream>>>(N, off, csr, yzg, perm,
                                       Wg + i * 256, bg + i * 16, Ws1 + i * 512,
                                       xr, xs);
  }
  k_final<<<nbF, 128, 0, stream>>>(N, xr, xs, cthn, sthn, batch, W1, b1, W2, b2, out);
}

// Round 13
// 699.250 us; speedup vs baseline: 1.1953x; 1.1953x over previous
//
#include <hip/hip_runtime.h>
#include <hip/hip_fp16.h>
#include <math.h>

#define NREP 16
#define RDIM 16
#define NS   16
#define NC   6
#define H1   144
#define DBINS 64

static __device__ __forceinline__ float leaky(float v) { return v > 0.0f ? v : 0.01f * v; }

// ---------- per-graph mean (LDS-binned: batch is sorted) ----------
__global__ void k_graph_sum(const float* __restrict__ pos, const int* __restrict__ batch,
                            int N, float* __restrict__ gsum, float* __restrict__ gcnt) {
  __shared__ float bx[320], by[320], bc[320];
  int t = threadIdx.x;
  int start = blockIdx.x * 256;
  int n = start + t;
  int b0 = batch[min(start, N - 1)];
  int span = batch[min(start + 255, N - 1)] - b0;   // batch sorted -> >=0
  bool useLds = (span < 320);
  if (useLds) {
    for (int i = t; i <= span; i += 256) { bx[i] = 0.f; by[i] = 0.f; bc[i] = 0.f; }
    __syncthreads();
    if (n < N) {
      int rb = batch[n] - b0;
      atomicAdd(&bx[rb], pos[2 * n + 0]);
      atomicAdd(&by[rb], pos[2 * n + 1]);
      atomicAdd(&bc[rb], 1.0f);
    }
    __syncthreads();
    for (int i = t; i <= span; i += 256) {
      if (bc[i] != 0.0f) {
        atomicAdd(&gsum[2 * (b0 + i) + 0], bx[i]);
        atomicAdd(&gsum[2 * (b0 + i) + 1], by[i]);
        atomicAdd(&gcnt[b0 + i], bc[i]);
      }
    }
  } else if (n < N) {
    int b = batch[n];
    atomicAdd(&gsum[2 * b + 0], pos[2 * n + 0]);
    atomicAdd(&gsum[2 * b + 1], pos[2 * n + 1]);
    atomicAdd(&gcnt[b], 1.0f);
  }
}

__global__ void k_center(const float* __restrict__ pos, const int* __restrict__ batch, int N,
                         const float* __restrict__ gsum, const float* __restrict__ gcnt,
                         float* __restrict__ posc, float* __restrict__ cthn, float* __restrict__ sthn) {
  int n = blockIdx.x * blockDim.x + threadIdx.x;
  if (n >= N) return;
  int b = batch[n];
  float invc = 1.0f / fmaxf(gcnt[b], 1.0f);
  float px = pos[2 * n + 0] - gsum[2 * b + 0] * invc;
  float py = pos[2 * n + 1] - gsum[2 * b + 1] * invc;
  posc[2 * n + 0] = px;
  posc[2 * n + 1] = py;
  float r = sqrtf(px * px + py * py);
  if (r > 0.0f) { cthn[n] = px / r; sthn[n] = py / r; }
  else          { cthn[n] = 1.0f;   sthn[n] = 0.0f; }
}

// ---------- CSR build ----------
__global__ void k_count(const int* __restrict__ ei, int E, int* __restrict__ cnt) {
  int e = blockIdx.x * blockDim.x + threadIdx.x;
  if (e >= E) return;
  atomicAdd(&cnt[ei[e]], 1);
}

// ---------- degree-sort permutation (64-bin counting sort, LDS-privatized) ----------
__global__ void k_dhist(const int* __restrict__ cnt, int N, int* __restrict__ dhist) {
  __shared__ int lh[DBINS];
  int t = threadIdx.x;
  int n = blockIdx.x * 256 + t;
  if (t < DBINS) lh[t] = 0;
  __syncthreads();
  if (n < N) atomicAdd(&lh[min(cnt[n], DBINS - 1)], 1);
  __syncthreads();
  if (t < DBINS && lh[t] > 0) atomicAdd(&dhist[t], lh[t]);
}

__global__ void k_dscan(const int* __restrict__ dhist, int* __restrict__ dcur) {
  __shared__ int sd[DBINS];
  int t = threadIdx.x;
  int v = dhist[t];
  sd[t] = v;
  __syncthreads();
  for (int o = 1; o < DBINS; o <<= 1) {
    int u = (t >= o) ? sd[t - o] : 0;
    __syncthreads();
    sd[t] += u;
    __syncthreads();
  }
  dcur[t] = sd[t] - v;   // exclusive base, doubles as cursor
}

// per-block chunk reservation: 256 LDS atomics + <=64 global atomics per block
__global__ void k_dfill(const int* __restrict__ cnt, int N, int* __restrict__ dcur,
                        int* __restrict__ perm) {
  __shared__ int lh[DBINS];
  __shared__ int base[DBINS];
  int t = threadIdx.x;
  int n = blockIdx.x * 256 + t;
  if (t < DBINS) lh[t] = 0;
  __syncthreads();
  int b = 0, lr = 0;
  if (n < N) {
    b = min(cnt[n], DBINS - 1);
    lr = atomicAdd(&lh[b], 1);           // local rank within (block, bin)
  }
  __syncthreads();
  if (t < DBINS && lh[t] > 0) base[t] = atomicAdd(&dcur[t], lh[t]);
  __syncthreads();
  if (n < N) perm[base[b] + lr] = n;
}

// ---------- parallel 3-phase exclusive scan of cnt[0..N) into off ----------
__global__ void k_scan1(const int* __restrict__ cnt, int N,
                        int* __restrict__ off, int* __restrict__ bsum) {
  __shared__ int sd[1024];
  int t = threadIdx.x;
  int i = blockIdx.x * 1024 + t;
  int v = (i < N) ? cnt[i] : 0;
  sd[t] = v;
  __syncthreads();
  for (int o = 1; o < 1024; o <<= 1) {
    int u = (t >= o) ? sd[t - o] : 0;
    __syncthreads();
    sd[t] += u;
    __syncthreads();
  }
  if (i < N) off[i] = sd[t] - v;          // block-local exclusive
  if (t == 1023) bsum[blockIdx.x] = sd[1023];
}

__global__ void k_scan2(int* __restrict__ bsum, int nb) {
  __shared__ int sd[1024];
  int t = threadIdx.x;
  int v = (t < nb) ? bsum[t] : 0;
  sd[t] = v;
  __syncthreads();
  for (int o = 1; o < 1024; o <<= 1) {
    int u = (t >= o) ? sd[t - o] : 0;
    __syncthreads();
    sd[t] += u;
    __syncthreads();
  }
  if (t < nb) bsum[t] = sd[t] - v;        // exclusive block bases
}

__global__ void k_scan3(int* __restrict__ off, const int* __restrict__ bsum, int N, int E) {
  int i = blockIdx.x * 1024 + threadIdx.x;
  if (i < N) off[i] += bsum[blockIdx.x];
  if (i == N) off[N] = E;                 // total is exactly E
}

// ---------- CSR pass A: scatter only the 4B edge id (one 64B line per row -> L2-merged) ----------
__global__ void k_scatter(const int* __restrict__ ei, int E,
                          const int* __restrict__ off, int* __restrict__ cursor,
                          int* __restrict__ eidx) {
  int e = blockIdx.x * blockDim.x + threadIdx.x;
  if (e >= E) return;
  int r = ei[e];
  int p = atomicAdd(&cursor[r], 1);
  eidx[off[r] + p] = e;
}

// ---------- CSR pass B: thread-per-node, sequential csr writes + node init (no atomics) ----------
// csr[k] = (sp' = sqrt2*sin(pi d)/(d+eps), c2 = 2*cos(pi d), col-bits, d)
__global__ void k_fill(int N, const int* __restrict__ off, const int* __restrict__ eidx,
                       const int* __restrict__ ei, int E,
                       const float* __restrict__ posc,
                       const float* __restrict__ Wer, const float* __restrict__ wse,
                       const float* __restrict__ bse,
                       float4* __restrict__ csr, float* __restrict__ xr, float* __restrict__ xs) {
  int n = blockIdx.x * blockDim.x + threadIdx.x;
  if (n >= N) return;
  int a = off[n], b = off[n + 1];
  float px = posc[2 * n + 0], py = posc[2 * n + 1];
  float C = 0.f, S = 0.f, D = 0.f;
  for (int k = a; k < b; k++) {
    int e = eidx[k];
    int cl = ei[E + e];
    float dx = px - posc[2 * cl + 0];
    float dy = py - posc[2 * cl + 1];
    float d = sqrtf(dx * dx + dy * dy);
    if (d > 0.0f) { float inv = 1.0f / d; C += dx * inv; S += dy * inv; }
    else          { C += 1.0f; }
    D += d;
    float sp, cp;
    sincospif(d, &sp, &cp);
    float spp = 1.41421356237309515f * sp / (d + 1e-8f);
    csr[k] = make_float4(spp, 2.0f * cp, __int_as_float(cl), d);  // streaming write
  }
  float id = 1.0f / fmaxf((float)(b - a), 1.0f);
  C *= id; S *= id;
  float dm = D * id;
  size_t nb = (size_t)n * (2 * NREP);
#pragma unroll
  for (int j = 0; j < NREP; j++) {
    float w0 = Wer[2 * j], w1 = Wer[2 * j + 1];
    xr[nb + 2 * j + 0] = C * w0 - S * w1;
    xr[nb + 2 * j + 1] = S * w0 + C * w1;
  }
  size_t ns = (size_t)n * NS;
#pragma unroll
  for (int t = 0; t < NS; t++) xs[ns + t] = leaky(dm * wse[t] + bse[t]);
}

// ---------- per-node precompute, fp16-packed: yzg = {h2(y0,y1), h2(z,gate)} ----------
__global__ void __launch_bounds__(256) k_pre(
    int N, const float* __restrict__ xr, const float* __restrict__ xs,
    const float* __restrict__ Wmix, const float* __restrict__ Ws1, const float* __restrict__ bs1,
    const float* __restrict__ Wgate, const float* __restrict__ bgate,
    uint2* __restrict__ yzg) {
  int idx = blockIdx.x * 256 + threadIdx.x;
  int n = idx >> 4, r = idx & 15;
  if (n >= N) return;
  float wmx[16], wsa[16], wgt[16];
  const float4* wm4 = (const float4*)(Wmix + r * 16);   // row r of Wmix (contiguous)
#pragma unroll
  for (int j = 0; j < 4; j++) {
    float4 w = wm4[j];
    wmx[4 * j + 0] = w.x; wmx[4 * j + 1] = w.y; wmx[4 * j + 2] = w.z; wmx[4 * j + 3] = w.w;
  }
#pragma unroll
  for (int q = 0; q < 16; q++) wsa[q] = Ws1[q * 16 + r];     // xs-part column r
#pragma unroll
  for (int q = 0; q < 16; q++) wgt[q] = Wgate[q * 16 + r];   // gate column r

  float x0[16], x1[16], xv[16];
  const float4* xr4 = (const float4*)(xr + (size_t)n * 32);
#pragma unroll
  for (int j = 0; j < 8; j++) {
    float4 u = xr4[j];
    x0[2 * j + 0] = u.x; x1[2 * j + 0] = u.y;
    x0[2 * j + 1] = u.z; x1[2 * j + 1] = u.w;
  }
  const float4* xs4 = (const float4*)(xs + (size_t)n * 16);
#pragma unroll
  for (int j = 0; j < 4; j++) {
    float4 u = xs4[j];
    xv[4 * j + 0] = u.x; xv[4 * j + 1] = u.y; xv[4 * j + 2] = u.z; xv[4 * j + 3] = u.w;
  }
  float y0 = 0.f, y1 = 0.f;
#pragma unroll
  for (int j = 0; j < 16; j++) { y0 += wmx[j] * x0[j]; y1 += wmx[j] * x1[j]; }
  float z = bs1[r], gt = bgate[r];
#pragma unroll
  for (int q = 0; q < 16; q++) { z += wsa[q] * xv[q]; gt += wgt[q] * xv[q]; }
  gt = 1.0f / (1.0f + __expf(-gt));
  __half2 hA = __floats2half2_rn(y0, y1);
  __half2 hB = __floats2half2_rn(z, gt);
  uint2 w2;
  w2.x = *(unsigned int*)&hA;
  w2.y = *(unsigned int*)&hB;
  yzg[(size_t)n * 16 + r] = w2;
}

// ---------- EqBlock layer: 16 lanes/node, degree-sorted, distance-2/3 prefetch ----------
__global__ void __launch_bounds__(256) k_layer(
    int N, const int* __restrict__ off, const float4* __restrict__ csr,
    const uint2* __restrict__ yzg, const int* __restrict__ perm,
    const float* __restrict__ Wg, const float* __restrict__ bg,
    const float* __restrict__ Ws1,   // layer base; demb rows are 16..31
    float* xr, float* xs) {
  int idx = blockIdx.x * 256 + threadIdx.x;
  int g = idx >> 4, r = idx & 15;
  if (g >= N) return;
  int n = perm[g];                      // degree-sorted: waves get equal-degree nodes
  float wg[16], ws[16];
#pragma unroll
  for (int q = 0; q < 16; q++) wg[q] = Wg[q * 16 + r];
#pragma unroll
  for (int q = 0; q < 16; q++) ws[q] = Ws1[(16 + q) * 16 + r];
  float bgr = bg[r];

  int a = off[n], bnd = off[n + 1];
  float acc0 = 0.f, acc1 = 0.f, accs = 0.f;
  if (a < bnd) {
    int last = bnd - 1;
    // deep pipeline: csr prefetched 3 ahead, yzg 2 ahead — both loads issue with
    // register-ready operands, Y consumed ~2 iterations (200+ cyc) after issue.
    float4 v0 = csr[a];
    float4 v1 = csr[min(a + 1, last)];
    float4 v2 = csr[min(a + 2, last)];
    uint2 Y0 = yzg[(size_t)__float_as_int(v0.z) * 16 + r];
    uint2 Y1 = yzg[(size_t)__float_as_int(v1.z) * 16 + r];
    for (int k = a; k < bnd; k++) {
      float4 v3 = csr[min(k + 3, last)];                       // prefetch csr
      uint2 Y2 = yzg[(size_t)__float_as_int(v2.z) * 16 + r];   // prefetch Y (v2 ready)
      // compute on v0 (radial chain independent of the gather)
      float skm1 = 0.f, sk = v0.x, c2 = v0.y;
      float g1 = bgr, dot = 0.f;
#pragma unroll
      for (int q = 0; q < RDIM; q++) {
        g1  = __builtin_fmaf(sk, wg[q], g1);
        dot = __builtin_fmaf(sk, ws[q], dot);
        float sn = __builtin_fmaf(c2, sk, -skm1);
        skm1 = sk; sk = sn;
      }
      // consume gathered Y0 only at the end of the iteration
      float2 f01 = __half22float2(*(__half2*)&Y0.x);
      float2 fzg = __half22float2(*(__half2*)&Y0.y);
      acc0 = __builtin_fmaf(g1, f01.x, acc0);
      acc1 = __builtin_fmaf(g1, f01.y, acc1);
      accs += leaky(dot + fzg.x);
      v0 = v1; v1 = v2; v2 = v3; Y0 = Y1; Y1 = Y2;
    }
  }
  float id = 1.0f / fmaxf((float)(bnd - a), 1.0f);
  uint2 Yg = yzg[(size_t)n * 16 + r];
  float gt = __half22float2(*(__half2*)&Yg.y).y;
  float2* xr2 = (float2*)xr;
  float2 x = xr2[(size_t)n * 16 + r];
  x.x += acc0 * id * gt;
  x.y += acc1 * id * gt;
  xr2[(size_t)n * 16 + r] = x;            // in-place safe: (n,r) written only by this thread
  xs[(size_t)n * 16 + r] += accs * id;
}

// ---------- final rotate-out + MLP (W1^T in LDS, 2-h ILP) + binned graph sum ----------
__global__ void __launch_bounds__(128) k_final(
    int N, const float* __restrict__ xr, const float* __restrict__ xs,
    const float* __restrict__ cthn, const float* __restrict__ sthn,
    const int* __restrict__ batch,
    const float* __restrict__ W1, const float* __restrict__ b1,
    const float* __restrict__ W2, const float* __restrict__ b2,
    float* __restrict__ out) {
  __shared__ float W1t[48 * H1];
  __shared__ float W2s[H1 * 6];
  __shared__ float b1s[H1];
  __shared__ float obin[320 * 6];
  int t = threadIdx.x;
  for (int i = t; i < 48 * H1; i += 128) { int q = i / H1, h = i - q * H1; W1t[h * 48 + q] = W1[i]; }
  for (int i = t; i < H1 * 6; i += 128) W2s[i] = W2[i];
  for (int i = t; i < H1; i += 128) b1s[i] = b1[i];

  int start = blockIdx.x * 128;
  int n = start + t;
  int b0 = batch[min(start, N - 1)];
  int span = batch[min(start + 127, N - 1)] - b0;
  bool useLds = (span < 320);
  if (useLds) for (int i = t; i < (span + 1) * 6; i += 128) obin[i] = 0.f;
  __syncthreads();

  float u[NC];
  bool act = (n < N);
  if (act) {
    float4 xcv[12];
    const float4* xs4 = (const float4*)(xs + (size_t)n * NS);
#pragma unroll
    for (int j = 0; j < 4; j++) xcv[j] = xs4[j];
    float c = cthn[n], s = sthn[n];
    const float4* xr4 = (const float4*)(xr + (size_t)n * 32);
#pragma unroll
    for (int j = 0; j < 8; j++) {
      float4 v = xr4[j];
      xcv[4 + j] = make_float4(c * v.x - s * v.y, s * v.x + c * v.y,
                               c * v.z - s * v.w, s * v.z + c * v.w);
    }
#pragma unroll
    for (int q = 0; q < NC; q++) u[q] = b2[q];
    for (int h = 0; h < H1; h += 2) {
      const float4* w0 = (const float4*)&W1t[h * 48];
      const float4* w1 = (const float4*)&W1t[(h + 1) * 48];
      float4 a0 = make_float4(0.f, 0.f, 0.f, 0.f);
      float4 a1 = make_float4(0.f, 0.f, 0.f, 0.f);
#pragma unroll
      for (int j = 0; j < 12; j++) {
        float4 x = xcv[j];
        float4 w = w0[j];
        a0.x += x.x * w.x; a0.y += x.y * w.y; a0.z += x.z * w.z; a0.w += x.w * w.w;
        float4 v = w1[j];
        a1.x += x.x * v.x; a1.y += x.y * v.y; a1.z += x.z * v.z; a1.w += x.w * v.w;
      }
      float aa0 = leaky((a0.x + a0.y) + (a0.z + a0.w) + b1s[h]);
      float aa1 = leaky((a1.x + a1.y) + (a1.z + a1.w) + b1s[h + 1]);
#pragma unroll
      for (int q = 0; q < NC; q++)
        u[q] += aa0 * W2s[h * 6 + q] + aa1 * W2s[(h + 1) * 6 + q];
    }
  }
  if (useLds) {
    if (act) {
      int rb = batch[n] - b0;
#pragma unroll
      for (int q = 0; q < NC; q++) atomicAdd(&obin[rb * 6 + q], u[q]);
    }
    __syncthreads();
    for (int i = t; i < (span + 1) * 6; i += 128) atomicAdd(&out[b0 * 6 + i], obin[i]);
  } else if (act) {
    int b = batch[n];
#pragma unroll
    for (int q = 0; q < NC; q++) atomicAdd(&out[b * 6 + q], u[q]);
  }
}

extern "C" void kernel_launch(void* const* d_in, const int* in_sizes, int n_in,
                              void* d_out, int out_size, void* d_ws, size_t ws_size,
                              hipStream_t stream) {
  const float* pos   = (const float*)d_in[0];
  const float* Wer   = (const float*)d_in[1];
  const float* wse   = (const float*)d_in[2];
  const float* bse   = (const float*)d_in[3];
  const float* Wg    = (const float*)d_in[4];
  const float* bg    = (const float*)d_in[5];
  const float* Wmix  = (const float*)d_in[6];
  const float* Wgate = (const float*)d_in[7];
  const float* bgate = (const float*)d_in[8];
  const float* Ws1   = (const float*)d_in[9];
  const float* bs1   = (const float*)d_in[10];
  const float* W1    = (const float*)d_in[11];
  const float* b1    = (const float*)d_in[12];
  const float* W2    = (const float*)d_in[13];
  const float* b2    = (const float*)d_in[14];
  const int*   ei    = (const int*)d_in[15];
  const int*   batch = (const int*)d_in[16];
  float* out = (float*)d_out;

  int N = in_sizes[0] / 2;
  int E = in_sizes[15] / 2;
  int G = out_size / NC;

  // ---- workspace layout (~62 MB for N=100k, E=1.6M) ----
  float* W = (float*)d_ws;
  size_t o = 0;
  float* gsum   = W + o; o += (size_t)2 * G;
  float* gcnt   = W + o; o += (size_t)G;
  int*   cnt    = (int*)(W + o); o += (size_t)N;
  int*   cursor = (int*)(W + o); o += (size_t)N;
  int*   dhist  = (int*)(W + o); o += (size_t)DBINS;
  size_t zero_bytes = o * 4;
  o = (o + 3) & ~(size_t)3;
  float* posc   = W + o; o += (size_t)2 * N;
  float* cthn   = W + o; o += (size_t)N;
  float* sthn   = W + o; o += (size_t)N;
  int*   off    = (int*)(W + o); o += (size_t)N + 1; o = (o + 3) & ~(size_t)3;
  int*   bsum   = (int*)(W + o); o += (size_t)1024;
  int*   dcur   = (int*)(W + o); o += (size_t)DBINS;
  int*   perm   = (int*)(W + o); o += (size_t)N; o = (o + 3) & ~(size_t)3;
  int*   eidx   = (int*)(W + o); o += (size_t)E; o = (o + 3) & ~(size_t)3;
  float4* csr   = (float4*)(W + o); o += (size_t)4 * E;
  uint2* yzg    = (uint2*)(W + o); o += (size_t)32 * N;
  float* xr     = W + o; o += (size_t)N * 32;
  float* xs     = W + o; o += (size_t)N * 16;
  (void)ws_size;

  hipMemsetAsync(d_ws, 0, zero_bytes, stream);
  hipMemsetAsync(d_out, 0, (size_t)out_size * 4, stream);

  int nbN  = (N + 255) / 256;
  int nbE  = (E + 255) / 256;
  int nbN16 = ((size_t)N * 16 + 255) / 256;
  int nbS  = (N + 1023) / 1024;           // scan blocks (98 for N=100k, <=1024 required)
  int nbS3 = (N + 1 + 1023) / 1024;
  int nbF  = (N + 127) / 128;             // k_final blocks

  k_graph_sum<<<nbN, 256, 0, stream>>>(pos, batch, N, gsum, gcnt);
  k_center<<<nbN, 256, 0, stream>>>(pos, batch, N, gsum, gcnt, posc, cthn, sthn);
  k_count<<<nbE, 256, 0, stream>>>(ei, E, cnt);
  k_dhist<<<nbN, 256, 0, stream>>>(cnt, N, dhist);
  k_dscan<<<1, DBINS, 0, stream>>>(dhist, dcur);
  k_dfill<<<nbN, 256, 0, stream>>>(cnt, N, dcur, perm);
  k_scan1<<<nbS, 1024, 0, stream>>>(cnt, N, off, bsum);
  k_scan2<<<1, 1024, 0, stream>>>(bsum, nbS);
  k_scan3<<<nbS3, 1024, 0, stream>>>(off, bsum, N, E);
  k_scatter<<<nbE, 256, 0, stream>>>(ei, E, off, cursor, eidx);
  k_fill<<<nbN, 256, 0, stream>>>(N, off, eidx, ei, E, posc, Wer, wse, bse, csr, xr, xs);

  for (int i = 0; i < 3; i++) {
    k_pre<<<nbN16, 256, 0, stream>>>(N, xr, xs,
                                     Wmix + i * 256, Ws1 + i * 512, bs1 + i * 16,
                                     Wgate + i * 256, bgate + i * 16, yzg);
    k_layer<<<nbN16, 256, 0, stream>>>(N, off, csr, yzg, perm,
                                       Wg + i * 256, bg + i * 16, Ws1 + i * 512,
                                       xr, xs);
  }
  k_final<<<nbF, 128, 0, stream>>>(N, xr, xs, cthn, sthn, batch, W1, b1, W2, b2, out);
}

// Round 14
// 610.691 us; speedup vs baseline: 1.3687x; 1.1450x over previous
//
#include <hip/hip_runtime.h>
#include <hip/hip_fp16.h>
#include <math.h>

#define NREP 16
#define RDIM 16
#define NS   16
#define NC   6
#define H1   144
#define DBINS 64

static __device__ __forceinline__ float leaky(float v) { return v > 0.0f ? v : 0.01f * v; }

// ---------- fused: per-graph mean (LDS-binned) + edge row count ----------
// grid = nbE blocks of 256: all blocks do the count part; first nbN do graph_sum.
__global__ void k_gsum_count(const float* __restrict__ pos, const int* __restrict__ batch,
                             int N, float* __restrict__ gsum, float* __restrict__ gcnt,
                             const int* __restrict__ ei, int E, int* __restrict__ cnt) {
  int t = threadIdx.x;
  int e = blockIdx.x * 256 + t;
  if (e < E) atomicAdd(&cnt[ei[e]], 1);

  __shared__ float bx[320], by[320], bc[320];
  int start = blockIdx.x * 256;
  if (start >= N) return;                  // only node-range blocks do graph_sum
  int n = start + t;
  int b0 = batch[min(start, N - 1)];
  int span = batch[min(start + 255, N - 1)] - b0;   // batch sorted -> >=0
  bool useLds = (span < 320);
  if (useLds) {
    for (int i = t; i <= span; i += 256) { bx[i] = 0.f; by[i] = 0.f; bc[i] = 0.f; }
    __syncthreads();
    if (n < N) {
      int rb = batch[n] - b0;
      atomicAdd(&bx[rb], pos[2 * n + 0]);
      atomicAdd(&by[rb], pos[2 * n + 1]);
      atomicAdd(&bc[rb], 1.0f);
    }
    __syncthreads();
    for (int i = t; i <= span; i += 256) {
      if (bc[i] != 0.0f) {
        atomicAdd(&gsum[2 * (b0 + i) + 0], bx[i]);
        atomicAdd(&gsum[2 * (b0 + i) + 1], by[i]);
        atomicAdd(&gcnt[b0 + i], bc[i]);
      }
    }
  } else if (n < N) {
    int b = batch[n];
    atomicAdd(&gsum[2 * b + 0], pos[2 * n + 0]);
    atomicAdd(&gsum[2 * b + 1], pos[2 * n + 1]);
    atomicAdd(&gcnt[b], 1.0f);
  }
}

__global__ void k_center(const float* __restrict__ pos, const int* __restrict__ batch, int N,
                         const float* __restrict__ gsum, const float* __restrict__ gcnt,
                         float* __restrict__ posc, float* __restrict__ cthn, float* __restrict__ sthn) {
  int n = blockIdx.x * blockDim.x + threadIdx.x;
  if (n >= N) return;
  int b = batch[n];
  float invc = 1.0f / fmaxf(gcnt[b], 1.0f);
  float px = pos[2 * n + 0] - gsum[2 * b + 0] * invc;
  float py = pos[2 * n + 1] - gsum[2 * b + 1] * invc;
  posc[2 * n + 0] = px;
  posc[2 * n + 1] = py;
  float r = sqrtf(px * px + py * py);
  if (r > 0.0f) { cthn[n] = px / r; sthn[n] = py / r; }
  else          { cthn[n] = 1.0f;   sthn[n] = 0.0f; }
}

// ---------- fused: degree histogram (LDS-privatized) + scan phase 1 ----------
__global__ void k_dhist_scan1(const int* __restrict__ cnt, int N,
                              int* __restrict__ dhist,
                              int* __restrict__ off, int* __restrict__ bsum) {
  __shared__ int lh[DBINS];
  __shared__ int sd[1024];
  int t = threadIdx.x;
  int i = blockIdx.x * 1024 + t;
  if (t < DBINS) lh[t] = 0;
  int v = (i < N) ? cnt[i] : 0;
  sd[t] = v;
  __syncthreads();
  if (i < N) atomicAdd(&lh[min(v, DBINS - 1)], 1);
  for (int o = 1; o < 1024; o <<= 1) {
    int u = (t >= o) ? sd[t - o] : 0;
    __syncthreads();
    sd[t] += u;
    __syncthreads();
  }
  if (i < N) off[i] = sd[t] - v;          // block-local exclusive
  if (t == 1023) bsum[blockIdx.x] = sd[1023];
  if (t < DBINS && lh[t] > 0) atomicAdd(&dhist[t], lh[t]);
}

// ---------- fused: degree-bin exclusive scan + block-sum exclusive scan ----------
__global__ void k_dscan_scan2(const int* __restrict__ dhist, int* __restrict__ dcur,
                              int* __restrict__ bsum, int nb) {
  __shared__ int s1[DBINS];
  __shared__ int s2[1024];
  int t = threadIdx.x;
  int v1 = (t < DBINS) ? dhist[t] : 0;
  if (t < DBINS) s1[t] = v1;
  int v2 = (t < nb) ? bsum[t] : 0;
  s2[t] = v2;
  __syncthreads();
  for (int o = 1; o < 1024; o <<= 1) {
    int u1 = (o < DBINS && t >= o && t < DBINS) ? s1[t - o] : 0;
    int u2 = (t >= o) ? s2[t - o] : 0;
    __syncthreads();
    if (o < DBINS && t < DBINS) s1[t] += u1;
    s2[t] += u2;
    __syncthreads();
  }
  if (t < DBINS) dcur[t] = s1[t] - v1;    // exclusive base, doubles as cursor
  if (t < nb) bsum[t] = s2[t] - v2;       // exclusive block bases
}

// ---------- fused: scan phase 3 (add block base) + degree-sort fill ----------
__global__ void k_dfill_scan3(int* __restrict__ off, const int* __restrict__ bsum,
                              int N, int E,
                              const int* __restrict__ cnt, int* __restrict__ dcur,
                              int* __restrict__ perm) {
  int t = threadIdx.x;
  int i = blockIdx.x * 1024 + t;
  if (i < N) off[i] += bsum[blockIdx.x];
  if (i == N) off[N] = E;                 // total is exactly E

  __shared__ int lh[DBINS];
  __shared__ int base[DBINS];
  if (t < DBINS) lh[t] = 0;
  __syncthreads();
  int b = 0, lr = 0;
  if (i < N) {
    b = min(cnt[i], DBINS - 1);
    lr = atomicAdd(&lh[b], 1);           // local rank within (block, bin)
  }
  __syncthreads();
  if (t < DBINS && lh[t] > 0) base[t] = atomicAdd(&dcur[t], lh[t]);
  __syncthreads();
  if (i < N) perm[base[b] + lr] = i;
}

// csr[k] = (sp' = sqrt2*sin(pi d)/(d+eps), c2 = 2*cos(pi d), col-bits, d)
// Single-pass scatter: pays the structural ~100MB line-granular writeback tax once.
__global__ void k_build(const float* __restrict__ posc, const int* __restrict__ ei, int E,
                        const int* __restrict__ off, int* __restrict__ cursor,
                        float4* __restrict__ csr) {
  int e = blockIdx.x * blockDim.x + threadIdx.x;
  if (e >= E) return;
  int r = ei[e], cl = ei[E + e];
  float dx = posc[2 * r + 0] - posc[2 * cl + 0];
  float dy = posc[2 * r + 1] - posc[2 * cl + 1];
  float d = sqrtf(dx * dx + dy * dy);
  float sp, cp;
  sincospif(d, &sp, &cp);
  float spp = 1.41421356237309515f * sp / (d + 1e-8f);
  int p = atomicAdd(&cursor[r], 1);
  csr[off[r] + p] = make_float4(spp, 2.0f * cp, __int_as_float(cl), d);
}

// ---------- node init (angle cos/sin from posc; d from csr.w) ----------
__global__ void k_node_init(int N, const int* __restrict__ off, const float4* __restrict__ csr,
                            const float* __restrict__ posc,
                            const float* __restrict__ Wer, const float* __restrict__ wse,
                            const float* __restrict__ bse,
                            float* __restrict__ xr, float* __restrict__ xs) {
  int n = blockIdx.x * blockDim.x + threadIdx.x;
  if (n >= N) return;
  int a = off[n], b = off[n + 1];
  float px = posc[2 * n + 0], py = posc[2 * n + 1];
  float C = 0.f, S = 0.f, D = 0.f;
  for (int k = a; k < b; k++) {
    float4 v = csr[k];
    int cl = __float_as_int(v.z);
    float d = v.w;
    if (d > 0.0f) {
      float inv = 1.0f / d;
      C += (px - posc[2 * cl + 0]) * inv;
      S += (py - posc[2 * cl + 1]) * inv;
    } else {
      C += 1.0f;
    }
    D += d;
  }
  float id = 1.0f / fmaxf((float)(b - a), 1.0f);
  C *= id; S *= id;
  float dm = D * id;
  size_t nb = (size_t)n * (2 * NREP);
#pragma unroll
  for (int j = 0; j < NREP; j++) {
    float w0 = Wer[2 * j], w1 = Wer[2 * j + 1];
    xr[nb + 2 * j + 0] = C * w0 - S * w1;
    xr[nb + 2 * j + 1] = S * w0 + C * w1;
  }
  size_t ns = (size_t)n * NS;
#pragma unroll
  for (int t = 0; t < NS; t++) xs[ns + t] = leaky(dm * wse[t] + bse[t]);
}

// ---------- per-node precompute, fp16-packed: yzg = {h2(y0,y1), h2(z,gate)} ----------
__global__ void __launch_bounds__(256) k_pre(
    int N, const float* __restrict__ xr, const float* __restrict__ xs,
    const float* __restrict__ Wmix, const float* __restrict__ Ws1, const float* __restrict__ bs1,
    const float* __restrict__ Wgate, const float* __restrict__ bgate,
    uint2* __restrict__ yzg) {
  int idx = blockIdx.x * 256 + threadIdx.x;
  int n = idx >> 4, r = idx & 15;
  if (n >= N) return;
  float wmx[16], wsa[16], wgt[16];
  const float4* wm4 = (const float4*)(Wmix + r * 16);   // row r of Wmix (contiguous)
#pragma unroll
  for (int j = 0; j < 4; j++) {
    float4 w = wm4[j];
    wmx[4 * j + 0] = w.x; wmx[4 * j + 1] = w.y; wmx[4 * j + 2] = w.z; wmx[4 * j + 3] = w.w;
  }
#pragma unroll
  for (int q = 0; q < 16; q++) wsa[q] = Ws1[q * 16 + r];     // xs-part column r
#pragma unroll
  for (int q = 0; q < 16; q++) wgt[q] = Wgate[q * 16 + r];   // gate column r

  float x0[16], x1[16], xv[16];
  const float4* xr4 = (const float4*)(xr + (size_t)n * 32);
#pragma unroll
  for (int j = 0; j < 8; j++) {
    float4 u = xr4[j];
    x0[2 * j + 0] = u.x; x1[2 * j + 0] = u.y;
    x0[2 * j + 1] = u.z; x1[2 * j + 1] = u.w;
  }
  const float4* xs4 = (const float4*)(xs + (size_t)n * 16);
#pragma unroll
  for (int j = 0; j < 4; j++) {
    float4 u = xs4[j];
    xv[4 * j + 0] = u.x; xv[4 * j + 1] = u.y; xv[4 * j + 2] = u.z; xv[4 * j + 3] = u.w;
  }
  float y0 = 0.f, y1 = 0.f;
#pragma unroll
  for (int j = 0; j < 16; j++) { y0 += wmx[j] * x0[j]; y1 += wmx[j] * x1[j]; }
  float z = bs1[r], gt = bgate[r];
#pragma unroll
  for (int q = 0; q < 16; q++) { z += wsa[q] * xv[q]; gt += wgt[q] * xv[q]; }
  gt = 1.0f / (1.0f + __expf(-gt));
  __half2 hA = __floats2half2_rn(y0, y1);
  __half2 hB = __floats2half2_rn(z, gt);
  uint2 w2;
  w2.x = *(unsigned int*)&hA;
  w2.y = *(unsigned int*)&hB;
  yzg[(size_t)n * 16 + r] = w2;
}

// ---------- EqBlock layer: 16 lanes/node, degree-sorted, distance-2/3 prefetch ----------
__global__ void __launch_bounds__(256) k_layer(
    int N, const int* __restrict__ off, const float4* __restrict__ csr,
    const uint2* __restrict__ yzg, const int* __restrict__ perm,
    const float* __restrict__ Wg, const float* __restrict__ bg,
    const float* __restrict__ Ws1,   // layer base; demb rows are 16..31
    float* xr, float* xs) {
  int idx = blockIdx.x * 256 + threadIdx.x;
  int g = idx >> 4, r = idx & 15;
  if (g >= N) return;
  int n = perm[g];                      // degree-sorted: waves get equal-degree nodes
  float wg[16], ws[16];
#pragma unroll
  for (int q = 0; q < 16; q++) wg[q] = Wg[q * 16 + r];
#pragma unroll
  for (int q = 0; q < 16; q++) ws[q] = Ws1[(16 + q) * 16 + r];
  float bgr = bg[r];

  int a = off[n], bnd = off[n + 1];
  float acc0 = 0.f, acc1 = 0.f, accs = 0.f;
  if (a < bnd) {
    int last = bnd - 1;
    // deep pipeline: csr prefetched 3 ahead, yzg 2 ahead — both loads issue with
    // register-ready operands, Y consumed ~2 iterations (200+ cyc) after issue.
    float4 v0 = csr[a];
    float4 v1 = csr[min(a + 1, last)];
    float4 v2 = csr[min(a + 2, last)];
    uint2 Y0 = yzg[(size_t)__float_as_int(v0.z) * 16 + r];
    uint2 Y1 = yzg[(size_t)__float_as_int(v1.z) * 16 + r];
    for (int k = a; k < bnd; k++) {
      float4 v3 = csr[min(k + 3, last)];                       // prefetch csr
      uint2 Y2 = yzg[(size_t)__float_as_int(v2.z) * 16 + r];   // prefetch Y (v2 ready)
      // compute on v0 (radial chain independent of the gather)
      float skm1 = 0.f, sk = v0.x, c2 = v0.y;
      float g1 = bgr, dot = 0.f;
#pragma unroll
      for (int q = 0; q < RDIM; q++) {
        g1  = __builtin_fmaf(sk, wg[q], g1);
        dot = __builtin_fmaf(sk, ws[q], dot);
        float sn = __builtin_fmaf(c2, sk, -skm1);
        skm1 = sk; sk = sn;
      }
      // consume gathered Y0 only at the end of the iteration
      float2 f01 = __half22float2(*(__half2*)&Y0.x);
      float2 fzg = __half22float2(*(__half2*)&Y0.y);
      acc0 = __builtin_fmaf(g1, f01.x, acc0);
      acc1 = __builtin_fmaf(g1, f01.y, acc1);
      accs += leaky(dot + fzg.x);
      v0 = v1; v1 = v2; v2 = v3; Y0 = Y1; Y1 = Y2;
    }
  }
  float id = 1.0f / fmaxf((float)(bnd - a), 1.0f);
  uint2 Yg = yzg[(size_t)n * 16 + r];
  float gt = __half22float2(*(__half2*)&Yg.y).y;
  float2* xr2 = (float2*)xr;
  float2 x = xr2[(size_t)n * 16 + r];
  x.x += acc0 * id * gt;
  x.y += acc1 * id * gt;
  xr2[(size_t)n * 16 + r] = x;            // in-place safe: (n,r) written only by this thread
  xs[(size_t)n * 16 + r] += accs * id;
}

// ---------- final rotate-out + MLP (W1^T in LDS, 2-h ILP) + binned graph sum ----------
__global__ void __launch_bounds__(128) k_final(
    int N, const float* __restrict__ xr, const float* __restrict__ xs,
    const float* __restrict__ cthn, const float* __restrict__ sthn,
    const int* __restrict__ batch,
    const float* __restrict__ W1, const float* __restrict__ b1,
    const float* __restrict__ W2, const float* __restrict__ b2,
    float* __restrict__ out) {
  __shared__ float W1t[48 * H1];
  __shared__ float W2s[H1 * 6];
  __shared__ float b1s[H1];
  __shared__ float obin[320 * 6];
  int t = threadIdx.x;
  for (int i = t; i < 48 * H1; i += 128) { int q = i / H1, h = i - q * H1; W1t[h * 48 + q] = W1[i]; }
  for (int i = t; i < H1 * 6; i += 128) W2s[i] = W2[i];
  for (int i = t; i < H1; i += 128) b1s[i] = b1[i];

  int start = blockIdx.x * 128;
  int n = start + t;
  int b0 = batch[min(start, N - 1)];
  int span = batch[min(start + 127, N - 1)] - b0;
  bool useLds = (span < 320);
  if (useLds) for (int i = t; i < (span + 1) * 6; i += 128) obin[i] = 0.f;
  __syncthreads();

  float u[NC];
  bool act = (n < N);
  if (act) {
    float4 xcv[12];
    const float4* xs4 = (const float4*)(xs + (size_t)n * NS);
#pragma unroll
    for (int j = 0; j < 4; j++) xcv[j] = xs4[j];
    float c = cthn[n], s = sthn[n];
    const float4* xr4 = (const float4*)(xr + (size_t)n * 32);
#pragma unroll
    for (int j = 0; j < 8; j++) {
      float4 v = xr4[j];
      xcv[4 + j] = make_float4(c * v.x - s * v.y, s * v.x + c * v.y,
                               c * v.z - s * v.w, s * v.z + c * v.w);
    }
#pragma unroll
    for (int q = 0; q < NC; q++) u[q] = b2[q];
    for (int h = 0; h < H1; h += 2) {
      const float4* w0 = (const float4*)&W1t[h * 48];
      const float4* w1 = (const float4*)&W1t[(h + 1) * 48];
      float4 a0 = make_float4(0.f, 0.f, 0.f, 0.f);
      float4 a1 = make_float4(0.f, 0.f, 0.f, 0.f);
#pragma unroll
      for (int j = 0; j < 12; j++) {
        float4 x = xcv[j];
        float4 w = w0[j];
        a0.x += x.x * w.x; a0.y += x.y * w.y; a0.z += x.z * w.z; a0.w += x.w * w.w;
        float4 v = w1[j];
        a1.x += x.x * v.x; a1.y += x.y * v.y; a1.z += x.z * v.z; a1.w += x.w * v.w;
      }
      float aa0 = leaky((a0.x + a0.y) + (a0.z + a0.w) + b1s[h]);
      float aa1 = leaky((a1.x + a1.y) + (a1.z + a1.w) + b1s[h + 1]);
#pragma unroll
      for (int q = 0; q < NC; q++)
        u[q] += aa0 * W2s[h * 6 + q] + aa1 * W2s[(h + 1) * 6 + q];
    }
  }
  if (useLds) {
    if (act) {
      int rb = batch[n] - b0;
#pragma unroll
      for (int q = 0; q < NC; q++) atomicAdd(&obin[rb * 6 + q], u[q]);
    }
    __syncthreads();
    for (int i = t; i < (span + 1) * 6; i += 128) atomicAdd(&out[b0 * 6 + i], obin[i]);
  } else if (act) {
    int b = batch[n];
#pragma unroll
    for (int q = 0; q < NC; q++) atomicAdd(&out[b * 6 + q], u[q]);
  }
}

extern "C" void kernel_launch(void* const* d_in, const int* in_sizes, int n_in,
                              void* d_out, int out_size, void* d_ws, size_t ws_size,
                              hipStream_t stream) {
  const float* pos   = (const float*)d_in[0];
  const float* Wer   = (const float*)d_in[1];
  const float* wse   = (const float*)d_in[2];
  const float* bse   = (const float*)d_in[3];
  const float* Wg    = (const float*)d_in[4];
  const float* bg    = (const float*)d_in[5];
  const float* Wmix  = (const float*)d_in[6];
  const float* Wgate = (const float*)d_in[7];
  const float* bgate = (const float*)d_in[8];
  const float* Ws1   = (const float*)d_in[9];
  const float* bs1   = (const float*)d_in[10];
  const float* W1    = (const float*)d_in[11];
  const float* b1    = (const float*)d_in[12];
  const float* W2    = (const float*)d_in[13];
  const float* b2    = (const float*)d_in[14];
  const int*   ei    = (const int*)d_in[15];
  const int*   batch = (const int*)d_in[16];
  float* out = (float*)d_out;

  int N = in_sizes[0] / 2;
  int E = in_sizes[15] / 2;
  int G = out_size / NC;

  // ---- workspace layout (~62 MB for N=100k, E=1.6M) ----
  float* W = (float*)d_ws;
  size_t o = 0;
  float* gsum   = W + o; o += (size_t)2 * G;
  float* gcnt   = W + o; o += (size_t)G;
  int*   cnt    = (int*)(W + o); o += (size_t)N;
  int*   cursor = (int*)(W + o); o += (size_t)N;
  int*   dhist  = (int*)(W + o); o += (size_t)DBINS;
  size_t zero_bytes = o * 4;
  o = (o + 3) & ~(size_t)3;
  float* posc   = W + o; o += (size_t)2 * N;
  float* cthn   = W + o; o += (size_t)N;
  float* sthn   = W + o; o += (size_t)N;
  int*   off    = (int*)(W + o); o += (size_t)N + 1; o = (o + 3) & ~(size_t)3;
  int*   bsum   = (int*)(W + o); o += (size_t)1024;
  int*   dcur   = (int*)(W + o); o += (size_t)DBINS;
  int*   perm   = (int*)(W + o); o += (size_t)N; o = (o + 3) & ~(size_t)3;
  float4* csr   = (float4*)(W + o); o += (size_t)4 * E;
  uint2* yzg    = (uint2*)(W + o); o += (size_t)32 * N;
  float* xr     = W + o; o += (size_t)N * 32;
  float* xs     = W + o; o += (size_t)N * 16;
  (void)ws_size;

  hipMemsetAsync(d_ws, 0, zero_bytes, stream);
  hipMemsetAsync(d_out, 0, (size_t)out_size * 4, stream);

  int nbN  = (N + 255) / 256;
  int nbE  = (E + 255) / 256;
  int nbN16 = ((size_t)N * 16 + 255) / 256;
  int nbS  = (N + 1023) / 1024;           // scan blocks (98 for N=100k, <=1024 required)
  int nbS3 = (N + 1 + 1023) / 1024;
  int nbF  = (N + 127) / 128;             // k_final blocks

  k_gsum_count<<<nbE, 256, 0, stream>>>(pos, batch, N, gsum, gcnt, ei, E, cnt);
  k_center<<<nbN, 256, 0, stream>>>(pos, batch, N, gsum, gcnt, posc, cthn, sthn);
  k_dhist_scan1<<<nbS, 1024, 0, stream>>>(cnt, N, dhist, off, bsum);
  k_dscan_scan2<<<1, 1024, 0, stream>>>(dhist, dcur, bsum, nbS);
  k_dfill_scan3<<<nbS3, 1024, 0, stream>>>(off, bsum, N, E, cnt, dcur, perm);
  k_build<<<nbE, 256, 0, stream>>>(posc, ei, E, off, cursor, csr);
  k_node_init<<<nbN, 256, 0, stream>>>(N, off, csr, posc, Wer, wse, bse, xr, xs);

  for (int i = 0; i < 3; i++) {
    k_pre<<<nbN16, 256, 0, stream>>>(N, xr, xs,
                                     Wmix + i * 256, Ws1 + i * 512, bs1 + i * 16,
                                     Wgate + i * 256, bgate + i * 16, yzg);
    k_layer<<<nbN16, 256, 0, stream>>>(N, off, csr, yzg, perm,
                                       Wg + i * 256, bg + i * 16, Ws1 + i * 512,
                                       xr, xs);
  }
  k_final<<<nbF, 128, 0, stream>>>(N, xr, xs, cthn, sthn, batch, W1, b1, W2, b2, out);
}

// Round 15
// 576.298 us; speedup vs baseline: 1.4503x; 1.0597x over previous
//
#include <hip/hip_runtime.h>
#include <hip/hip_fp16.h>
#include <math.h>

#define NREP 16
#define RDIM 16
#define NS   16
#define NC   6
#define H1   144
#define DBINS 64

static __device__ __forceinline__ float leaky(float v) { return v > 0.0f ? v : 0.01f * v; }

// ---------- fused: per-graph mean (LDS-binned) + edge row count ----------
__global__ void k_gsum_count(const float* __restrict__ pos, const int* __restrict__ batch,
                             int N, float* __restrict__ gsum, float* __restrict__ gcnt,
                             const int* __restrict__ ei, int E, int* __restrict__ cnt) {
  int t = threadIdx.x;
  int e = blockIdx.x * 256 + t;
  if (e < E) atomicAdd(&cnt[ei[e]], 1);

  __shared__ float bx[320], by[320], bc[320];
  int start = blockIdx.x * 256;
  if (start >= N) return;
  int n = start + t;
  int b0 = batch[min(start, N - 1)];
  int span = batch[min(start + 255, N - 1)] - b0;
  bool useLds = (span < 320);
  if (useLds) {
    for (int i = t; i <= span; i += 256) { bx[i] = 0.f; by[i] = 0.f; bc[i] = 0.f; }
    __syncthreads();
    if (n < N) {
      int rb = batch[n] - b0;
      atomicAdd(&bx[rb], pos[2 * n + 0]);
      atomicAdd(&by[rb], pos[2 * n + 1]);
      atomicAdd(&bc[rb], 1.0f);
    }
    __syncthreads();
    for (int i = t; i <= span; i += 256) {
      if (bc[i] != 0.0f) {
        atomicAdd(&gsum[2 * (b0 + i) + 0], bx[i]);
        atomicAdd(&gsum[2 * (b0 + i) + 1], by[i]);
        atomicAdd(&gcnt[b0 + i], bc[i]);
      }
    }
  } else if (n < N) {
    int b = batch[n];
    atomicAdd(&gsum[2 * b + 0], pos[2 * n + 0]);
    atomicAdd(&gsum[2 * b + 1], pos[2 * n + 1]);
    atomicAdd(&gcnt[b], 1.0f);
  }
}

// ---------- fused: center + degree histogram + scan phase 1 ----------
__global__ void k_center_dhist_scan1(
    const float* __restrict__ pos, const int* __restrict__ batch, int N,
    const float* __restrict__ gsum, const float* __restrict__ gcnt,
    float* __restrict__ posc, float* __restrict__ cthn, float* __restrict__ sthn,
    const int* __restrict__ cnt, int* __restrict__ dhist,
    int* __restrict__ off, int* __restrict__ bsum) {
  __shared__ int lh[DBINS];
  __shared__ int sd[1024];
  int t = threadIdx.x;
  int i = blockIdx.x * 1024 + t;
  if (t < DBINS) lh[t] = 0;
  int v = (i < N) ? cnt[i] : 0;
  sd[t] = v;
  if (i < N) {
    int b = batch[i];
    float invc = 1.0f / fmaxf(gcnt[b], 1.0f);
    float px = pos[2 * i + 0] - gsum[2 * b + 0] * invc;
    float py = pos[2 * i + 1] - gsum[2 * b + 1] * invc;
    posc[2 * i + 0] = px;
    posc[2 * i + 1] = py;
    float r = sqrtf(px * px + py * py);
    if (r > 0.0f) { cthn[i] = px / r; sthn[i] = py / r; }
    else          { cthn[i] = 1.0f;  sthn[i] = 0.0f; }
  }
  __syncthreads();
  if (i < N) atomicAdd(&lh[min(v, DBINS - 1)], 1);
  for (int o = 1; o < 1024; o <<= 1) {
    int u = (t >= o) ? sd[t - o] : 0;
    __syncthreads();
    sd[t] += u;
    __syncthreads();
  }
  if (i < N) off[i] = sd[t] - v;
  if (t == 1023) bsum[blockIdx.x] = sd[1023];
  if (t < DBINS && lh[t] > 0) atomicAdd(&dhist[t], lh[t]);
}

// ---------- fused: degree-bin exclusive scan + block-sum exclusive scan ----------
__global__ void k_dscan_scan2(const int* __restrict__ dhist, int* __restrict__ dcur,
                              int* __restrict__ bsum, int nb) {
  __shared__ int s1[DBINS];
  __shared__ int s2[1024];
  int t = threadIdx.x;
  int v1 = (t < DBINS) ? dhist[t] : 0;
  if (t < DBINS) s1[t] = v1;
  int v2 = (t < nb) ? bsum[t] : 0;
  s2[t] = v2;
  __syncthreads();
  for (int o = 1; o < 1024; o <<= 1) {
    int u1 = (o < DBINS && t >= o && t < DBINS) ? s1[t - o] : 0;
    int u2 = (t >= o) ? s2[t - o] : 0;
    __syncthreads();
    if (o < DBINS && t < DBINS) s1[t] += u1;
    s2[t] += u2;
    __syncthreads();
  }
  if (t < DBINS) dcur[t] = s1[t] - v1;
  if (t < nb) bsum[t] = s2[t] - v2;
}

// ---------- fused: scan phase 3 + degree-sort fill ----------
__global__ void k_dfill_scan3(int* __restrict__ off, const int* __restrict__ bsum,
                              int N, int E,
                              const int* __restrict__ cnt, int* __restrict__ dcur,
                              int* __restrict__ perm) {
  int t = threadIdx.x;
  int i = blockIdx.x * 1024 + t;
  if (i < N) off[i] += bsum[blockIdx.x];
  if (i == N) off[N] = E;

  __shared__ int lh[DBINS];
  __shared__ int base[DBINS];
  if (t < DBINS) lh[t] = 0;
  __syncthreads();
  int b = 0, lr = 0;
  if (i < N) {
    b = min(cnt[i], DBINS - 1);
    lr = atomicAdd(&lh[b], 1);
  }
  __syncthreads();
  if (t < DBINS && lh[t] > 0) base[t] = atomicAdd(&dcur[t], lh[t]);
  __syncthreads();
  if (i < N) perm[base[b] + lr] = i;
}

// csr[k] = (sp' = sqrt2*sin(pi d)/(d+eps), c2 = 2*cos(pi d), col-bits, d)
// Single-pass scatter: ~1 line-writeback per store (64B × E ≈ 102MB) — structural floor.
__global__ void k_build(const float* __restrict__ posc, const int* __restrict__ ei, int E,
                        const int* __restrict__ off, int* __restrict__ cursor,
                        float4* __restrict__ csr) {
  int e = blockIdx.x * blockDim.x + threadIdx.x;
  if (e >= E) return;
  int r = ei[e], cl = ei[E + e];
  float dx = posc[2 * r + 0] - posc[2 * cl + 0];
  float dy = posc[2 * r + 1] - posc[2 * cl + 1];
  float d = sqrtf(dx * dx + dy * dy);
  float sp, cp;
  sincospif(d, &sp, &cp);
  float spp = 1.41421356237309515f * sp / (d + 1e-8f);
  int p = atomicAdd(&cursor[r], 1);
  csr[off[r] + p] = make_float4(spp, 2.0f * cp, __int_as_float(cl), d);
}

// ---------- node init (angle cos/sin from posc; d from csr.w) ----------
__global__ void k_node_init(int N, const int* __restrict__ off, const float4* __restrict__ csr,
                            const float* __restrict__ posc,
                            const float* __restrict__ Wer, const float* __restrict__ wse,
                            const float* __restrict__ bse,
                            float* __restrict__ xr, float* __restrict__ xs) {
  int n = blockIdx.x * blockDim.x + threadIdx.x;
  if (n >= N) return;
  int a = off[n], b = off[n + 1];
  float px = posc[2 * n + 0], py = posc[2 * n + 1];
  float C = 0.f, S = 0.f, D = 0.f;
  for (int k = a; k < b; k++) {
    float4 v = csr[k];
    int cl = __float_as_int(v.z);
    float d = v.w;
    if (d > 0.0f) {
      float inv = 1.0f / d;
      C += (px - posc[2 * cl + 0]) * inv;
      S += (py - posc[2 * cl + 1]) * inv;
    } else {
      C += 1.0f;
    }
    D += d;
  }
  float id = 1.0f / fmaxf((float)(b - a), 1.0f);
  C *= id; S *= id;
  float dm = D * id;
  size_t nb = (size_t)n * (2 * NREP);
#pragma unroll
  for (int j = 0; j < NREP; j++) {
    float w0 = Wer[2 * j], w1 = Wer[2 * j + 1];
    xr[nb + 2 * j + 0] = C * w0 - S * w1;
    xr[nb + 2 * j + 1] = S * w0 + C * w1;
  }
  size_t ns = (size_t)n * NS;
#pragma unroll
  for (int t = 0; t < NS; t++) xs[ns + t] = leaky(dm * wse[t] + bse[t]);
}

// ---------- per-node precompute for layer 0 only, fp16-packed ----------
__global__ void __launch_bounds__(256) k_pre(
    int N, const float* __restrict__ xr, const float* __restrict__ xs,
    const float* __restrict__ Wmix, const float* __restrict__ Ws1, const float* __restrict__ bs1,
    const float* __restrict__ Wgate, const float* __restrict__ bgate,
    uint2* __restrict__ yzg) {
  int idx = blockIdx.x * 256 + threadIdx.x;
  int n = idx >> 4, r = idx & 15;
  if (n >= N) return;
  float wmx[16], wsa[16], wgt[16];
  const float4* wm4 = (const float4*)(Wmix + r * 16);
#pragma unroll
  for (int j = 0; j < 4; j++) {
    float4 w = wm4[j];
    wmx[4 * j + 0] = w.x; wmx[4 * j + 1] = w.y; wmx[4 * j + 2] = w.z; wmx[4 * j + 3] = w.w;
  }
#pragma unroll
  for (int q = 0; q < 16; q++) wsa[q] = Ws1[q * 16 + r];
#pragma unroll
  for (int q = 0; q < 16; q++) wgt[q] = Wgate[q * 16 + r];

  float x0[16], x1[16], xv[16];
  const float4* xr4 = (const float4*)(xr + (size_t)n * 32);
#pragma unroll
  for (int j = 0; j < 8; j++) {
    float4 u = xr4[j];
    x0[2 * j + 0] = u.x; x1[2 * j + 0] = u.y;
    x0[2 * j + 1] = u.z; x1[2 * j + 1] = u.w;
  }
  const float4* xs4 = (const float4*)(xs + (size_t)n * 16);
#pragma unroll
  for (int j = 0; j < 4; j++) {
    float4 u = xs4[j];
    xv[4 * j + 0] = u.x; xv[4 * j + 1] = u.y; xv[4 * j + 2] = u.z; xv[4 * j + 3] = u.w;
  }
  float y0 = 0.f, y1 = 0.f;
#pragma unroll
  for (int j = 0; j < 16; j++) { y0 += wmx[j] * x0[j]; y1 += wmx[j] * x1[j]; }
  float z = bs1[r], gt = bgate[r];
#pragma unroll
  for (int q = 0; q < 16; q++) { z += wsa[q] * xv[q]; gt += wgt[q] * xv[q]; }
  gt = 1.0f / (1.0f + __expf(-gt));
  __half2 hA = __floats2half2_rn(y0, y1);
  __half2 hB = __floats2half2_rn(z, gt);
  uint2 w2;
  w2.x = *(unsigned int*)&hA;
  w2.y = *(unsigned int*)&hB;
  yzg[(size_t)n * 16 + r] = w2;
}

// ---------- EqBlock layer + fused next-layer pre (shuffle form, yzg ping-pong) ----------
__global__ void __launch_bounds__(256) k_layer(
    int N, const int* __restrict__ off, const float4* __restrict__ csr,
    const uint2* __restrict__ yzg, const int* __restrict__ perm,
    const float* __restrict__ Wg, const float* __restrict__ bg,
    const float* __restrict__ Ws1,   // this layer; demb rows are 16..31
    float* xr, float* xs,
    int write_next, uint2* __restrict__ yzg_out,
    const float* __restrict__ Wmixn, const float* __restrict__ Ws1n,
    const float* __restrict__ bs1n,
    const float* __restrict__ Wgaten, const float* __restrict__ bgaten) {
  int idx = blockIdx.x * 256 + threadIdx.x;
  int g = idx >> 4, r = idx & 15;
  if (g >= N) return;
  int n = perm[g];                      // degree-sorted: waves get equal-degree nodes
  float wg[16], ws[16];
#pragma unroll
  for (int q = 0; q < 16; q++) wg[q] = Wg[q * 16 + r];
#pragma unroll
  for (int q = 0; q < 16; q++) ws[q] = Ws1[(16 + q) * 16 + r];
  float bgr = bg[r];

  int a = off[n], bnd = off[n + 1];
  float acc0 = 0.f, acc1 = 0.f, accs = 0.f;
  if (a < bnd) {
    int last = bnd - 1;
    float4 v0 = csr[a];
    float4 v1 = csr[min(a + 1, last)];
    float4 v2 = csr[min(a + 2, last)];
    uint2 Y0 = yzg[(size_t)__float_as_int(v0.z) * 16 + r];
    uint2 Y1 = yzg[(size_t)__float_as_int(v1.z) * 16 + r];
    for (int k = a; k < bnd; k++) {
      float4 v3 = csr[min(k + 3, last)];
      uint2 Y2 = yzg[(size_t)__float_as_int(v2.z) * 16 + r];
      float skm1 = 0.f, sk = v0.x, c2 = v0.y;
      float g1 = bgr, dot = 0.f;
#pragma unroll
      for (int q = 0; q < RDIM; q++) {
        g1  = __builtin_fmaf(sk, wg[q], g1);
        dot = __builtin_fmaf(sk, ws[q], dot);
        float sn = __builtin_fmaf(c2, sk, -skm1);
        skm1 = sk; sk = sn;
      }
      float2 f01 = __half22float2(*(__half2*)&Y0.x);
      float2 fzg = __half22float2(*(__half2*)&Y0.y);
      acc0 = __builtin_fmaf(g1, f01.x, acc0);
      acc1 = __builtin_fmaf(g1, f01.y, acc1);
      accs += leaky(dot + fzg.x);
      v0 = v1; v1 = v2; v2 = v3; Y0 = Y1; Y1 = Y2;
    }
  }
  float id = 1.0f / fmaxf((float)(bnd - a), 1.0f);
  uint2 Yg = yzg[(size_t)n * 16 + r];
  float gt = __half22float2(*(__half2*)&Yg.y).y;
  float2* xr2 = (float2*)xr;
  float2 x = xr2[(size_t)n * 16 + r];
  x.x += acc0 * id * gt;
  x.y += acc1 * id * gt;
  xr2[(size_t)n * 16 + r] = x;            // in-place safe: (n,r) written only by this thread
  float s_new = xs[(size_t)n * 16 + r] + accs * id;
  xs[(size_t)n * 16 + r] = s_new;

  if (write_next) {
    // fused k_pre for next layer: cross-r via 16-wide shuffles (same sum order as k_pre)
    float wmxn[16], wsan[16], wgtn[16];
#pragma unroll
    for (int q = 0; q < 16; q++) wmxn[q] = Wmixn[r * 16 + q];
#pragma unroll
    for (int q = 0; q < 16; q++) wsan[q] = Ws1n[q * 16 + r];
#pragma unroll
    for (int q = 0; q < 16; q++) wgtn[q] = Wgaten[q * 16 + r];
    float y0 = 0.f, y1 = 0.f;
    float z = bs1n[r], gtn = bgaten[r];
#pragma unroll
    for (int j = 0; j < 16; j++) {
      float xj0 = __shfl(x.x, j, 16);
      float xj1 = __shfl(x.y, j, 16);
      float sj  = __shfl(s_new, j, 16);
      y0 += wmxn[j] * xj0;
      y1 += wmxn[j] * xj1;
      z  += wsan[j] * sj;
      gtn += wgtn[j] * sj;
    }
    gtn = 1.0f / (1.0f + __expf(-gtn));
    __half2 hA = __floats2half2_rn(y0, y1);
    __half2 hB = __floats2half2_rn(z, gtn);
    uint2 w2;
    w2.x = *(unsigned int*)&hA;
    w2.y = *(unsigned int*)&hB;
    yzg_out[(size_t)n * 16 + r] = w2;
  }
}

// ---------- final rotate-out + MLP (W1^T in LDS, 2-h ILP) + binned graph sum ----------
__global__ void __launch_bounds__(128) k_final(
    int N, const float* __restrict__ xr, const float* __restrict__ xs,
    const float* __restrict__ cthn, const float* __restrict__ sthn,
    const int* __restrict__ batch,
    const float* __restrict__ W1, const float* __restrict__ b1,
    const float* __restrict__ W2, const float* __restrict__ b2,
    float* __restrict__ out) {
  __shared__ float W1t[48 * H1];
  __shared__ float W2s[H1 * 6];
  __shared__ float b1s[H1];
  __shared__ float obin[320 * 6];
  int t = threadIdx.x;
  for (int i = t; i < 48 * H1; i += 128) { int q = i / H1, h = i - q * H1; W1t[h * 48 + q] = W1[i]; }
  for (int i = t; i < H1 * 6; i += 128) W2s[i] = W2[i];
  for (int i = t; i < H1; i += 128) b1s[i] = b1[i];

  int start = blockIdx.x * 128;
  int n = start + t;
  int b0 = batch[min(start, N - 1)];
  int span = batch[min(start + 127, N - 1)] - b0;
  bool useLds = (span < 320);
  if (useLds) for (int i = t; i < (span + 1) * 6; i += 128) obin[i] = 0.f;
  __syncthreads();

  float u[NC];
  bool act = (n < N);
  if (act) {
    float4 xcv[12];
    const float4* xs4 = (const float4*)(xs + (size_t)n * NS);
#pragma unroll
    for (int j = 0; j < 4; j++) xcv[j] = xs4[j];
    float c = cthn[n], s = sthn[n];
    const float4* xr4 = (const float4*)(xr + (size_t)n * 32);
#pragma unroll
    for (int j = 0; j < 8; j++) {
      float4 v = xr4[j];
      xcv[4 + j] = make_float4(c * v.x - s * v.y, s * v.x + c * v.y,
                               c * v.z - s * v.w, s * v.z + c * v.w);
    }
#pragma unroll
    for (int q = 0; q < NC; q++) u[q] = b2[q];
    for (int h = 0; h < H1; h += 2) {
      const float4* w0 = (const float4*)&W1t[h * 48];
      const float4* w1 = (const float4*)&W1t[(h + 1) * 48];
      float4 a0 = make_float4(0.f, 0.f, 0.f, 0.f);
      float4 a1 = make_float4(0.f, 0.f, 0.f, 0.f);
#pragma unroll
      for (int j = 0; j < 12; j++) {
        float4 x = xcv[j];
        float4 w = w0[j];
        a0.x += x.x * w.x; a0.y += x.y * w.y; a0.z += x.z * w.z; a0.w += x.w * w.w;
        float4 v = w1[j];
        a1.x += x.x * v.x; a1.y += x.y * v.y; a1.z += x.z * v.z; a1.w += x.w * v.w;
      }
      float aa0 = leaky((a0.x + a0.y) + (a0.z + a0.w) + b1s[h]);
      float aa1 = leaky((a1.x + a1.y) + (a1.z + a1.w) + b1s[h + 1]);
#pragma unroll
      for (int q = 0; q < NC; q++)
        u[q] += aa0 * W2s[h * 6 + q] + aa1 * W2s[(h + 1) * 6 + q];
    }
  }
  if (useLds) {
    if (act) {
      int rb = batch[n] - b0;
#pragma unroll
      for (int q = 0; q < NC; q++) atomicAdd(&obin[rb * 6 + q], u[q]);
    }
    __syncthreads();
    for (int i = t; i < (span + 1) * 6; i += 128) atomicAdd(&out[b0 * 6 + i], obin[i]);
  } else if (act) {
    int b = batch[n];
#pragma unroll
    for (int q = 0; q < NC; q++) atomicAdd(&out[b * 6 + q], u[q]);
  }
}

extern "C" void kernel_launch(void* const* d_in, const int* in_sizes, int n_in,
                              void* d_out, int out_size, void* d_ws, size_t ws_size,
                              hipStream_t stream) {
  const float* pos   = (const float*)d_in[0];
  const float* Wer   = (const float*)d_in[1];
  const float* wse   = (const float*)d_in[2];
  const float* bse   = (const float*)d_in[3];
  const float* Wg    = (const float*)d_in[4];
  const float* bg    = (const float*)d_in[5];
  const float* Wmix  = (const float*)d_in[6];
  const float* Wgate = (const float*)d_in[7];
  const float* bgate = (const float*)d_in[8];
  const float* Ws1   = (const float*)d_in[9];
  const float* bs1   = (const float*)d_in[10];
  const float* W1    = (const float*)d_in[11];
  const float* b1    = (const float*)d_in[12];
  const float* W2    = (const float*)d_in[13];
  const float* b2    = (const float*)d_in[14];
  const int*   ei    = (const int*)d_in[15];
  const int*   batch = (const int*)d_in[16];
  float* out = (float*)d_out;

  int N = in_sizes[0] / 2;
  int E = in_sizes[15] / 2;
  int G = out_size / NC;

  // ---- workspace layout (~75 MB for N=100k, E=1.6M — R5 proved 74MB safe) ----
  float* W = (float*)d_ws;
  size_t o = 0;
  float* gsum   = W + o; o += (size_t)2 * G;
  float* gcnt   = W + o; o += (size_t)G;
  int*   cnt    = (int*)(W + o); o += (size_t)N;
  int*   cursor = (int*)(W + o); o += (size_t)N;
  int*   dhist  = (int*)(W + o); o += (size_t)DBINS;
  size_t zero_bytes = o * 4;
  o = (o + 3) & ~(size_t)3;
  float* posc   = W + o; o += (size_t)2 * N;
  float* cthn   = W + o; o += (size_t)N;
  float* sthn   = W + o; o += (size_t)N;
  int*   off    = (int*)(W + o); o += (size_t)N + 1; o = (o + 3) & ~(size_t)3;
  int*   bsum   = (int*)(W + o); o += (size_t)1024;
  int*   dcur   = (int*)(W + o); o += (size_t)DBINS;
  int*   perm   = (int*)(W + o); o += (size_t)N; o = (o + 3) & ~(size_t)3;
  float4* csr   = (float4*)(W + o); o += (size_t)4 * E;
  uint2* yzgA   = (uint2*)(W + o); o += (size_t)32 * N;
  uint2* yzgB   = (uint2*)(W + o); o += (size_t)32 * N;
  float* xr     = W + o; o += (size_t)N * 32;
  float* xs     = W + o; o += (size_t)N * 16;
  (void)ws_size;

  hipMemsetAsync(d_ws, 0, zero_bytes, stream);
  hipMemsetAsync(d_out, 0, (size_t)out_size * 4, stream);

  int nbN  = (N + 255) / 256;
  int nbE  = (E + 255) / 256;
  int nbN16 = ((size_t)N * 16 + 255) / 256;
  int nbS  = (N + 1023) / 1024;
  int nbS3 = (N + 1 + 1023) / 1024;
  int nbF  = (N + 127) / 128;

  k_gsum_count<<<nbE, 256, 0, stream>>>(pos, batch, N, gsum, gcnt, ei, E, cnt);
  k_center_dhist_scan1<<<nbS, 1024, 0, stream>>>(pos, batch, N, gsum, gcnt,
                                                 posc, cthn, sthn, cnt, dhist, off, bsum);
  k_dscan_scan2<<<1, 1024, 0, stream>>>(dhist, dcur, bsum, nbS);
  k_dfill_scan3<<<nbS3, 1024, 0, stream>>>(off, bsum, N, E, cnt, dcur, perm);
  k_build<<<nbE, 256, 0, stream>>>(posc, ei, E, off, cursor, csr);
  k_node_init<<<nbN, 256, 0, stream>>>(N, off, csr, posc, Wer, wse, bse, xr, xs);
  k_pre<<<nbN16, 256, 0, stream>>>(N, xr, xs, Wmix, Ws1, bs1, Wgate, bgate, yzgA);

  // layer 0: read A, write B (fused pre for layer 1)
  k_layer<<<nbN16, 256, 0, stream>>>(N, off, csr, yzgA, perm,
                                     Wg, bg, Ws1, xr, xs,
                                     1, yzgB,
                                     Wmix + 256, Ws1 + 512, bs1 + 16, Wgate + 256, bgate + 16);
  // layer 1: read B, write A (fused pre for layer 2)
  k_layer<<<nbN16, 256, 0, stream>>>(N, off, csr, yzgB, perm,
                                     Wg + 256, bg + 16, Ws1 + 512, xr, xs,
                                     1, yzgA,
                                     Wmix + 512, Ws1 + 1024, bs1 + 32, Wgate + 512, bgate + 32);
  // layer 2: read A, no next
  k_layer<<<nbN16, 256, 0, stream>>>(N, off, csr, yzgA, perm,
                                     Wg + 512, bg + 32, Ws1 + 1024, xr, xs,
                                     0, yzgB,
                                     Wmix, Ws1, bs1, Wgate, bgate);

  k_final<<<nbF, 128, 0, stream>>>(N, xr, xs, cthn, sthn, batch, W1, b1, W2, b2, out);
}